// Round 2
// 183.604 us; speedup vs baseline: 1.0272x; 1.0272x over previous
//
#include <hip/hip_runtime.h>

// PillarFeatureNet: linear(9->64, no bias) -> BN1d (training stats over B*Cout
// rows, P*N=64 cols) -> ReLU -> max over N.
//
// Round-2 structure (cooperative launch abandoned — it silently no-op'd):
//   pfn_prep   : G = W^T W, wsum = col-sums of W, zero shadow accumulators
//   pfn_stats  : Gram-trick stats (VERBATIM from the passing round-0 kernel)
//   pfn_main   : inline BN-coefficient finalize (per block, L2-hot) + output.
//                Weights via wave-uniform s_loads (no LDS in hot loop).
//
// ws float layout:
//   [0,81)      G (9x9 row-major)
//   [81,90)     wsum
//   [96,1120)   8 shadow copies x 128 accumulator floats
//               copy s, col j, t(0=d-sum,1=q-sum): 96 + s*128 + j*2 + t

#define EPS_BN 1e-5f

__global__ __launch_bounds__(64) void pfn_prep(const float* __restrict__ W,
                                               float* __restrict__ ws) {
    __shared__ float prod[64][90];
    const int o = threadIdx.x;  // 0..63
    float w[9];
#pragma unroll
    for (int c = 0; c < 9; ++c) w[c] = W[o * 9 + c];
#pragma unroll
    for (int c = 0; c < 9; ++c)
#pragma unroll
        for (int c2 = 0; c2 < 9; ++c2) prod[o][c * 9 + c2] = w[c] * w[c2];
#pragma unroll
    for (int c = 0; c < 9; ++c) prod[o][81 + c] = w[c];
    // zero the 8 shadow accumulator copies: 1024 floats
#pragma unroll
    for (int k = 0; k < 16; ++k) ws[96 + o * 16 + k] = 0.f;
    __syncthreads();
    for (int col = o; col < 90; col += 64) {
        float s = 0.f;
        for (int r = 0; r < 64; ++r) s += prod[r][col];
        ws[col] = s;
    }
}

__global__ __launch_bounds__(256) void pfn_stats(const float* __restrict__ pillars,
                                                 const float* __restrict__ gw,
                                                 float* __restrict__ acc8,
                                                 int npairs) {
    const int tid = threadIdx.x;
    const int lane = tid & 63;
    const int p = lane & 31;
    const int bsub = lane >> 5;

    // wave-uniform: expect s_load / SGPR residency (separate __restrict__ ptr,
    // never written by this kernel)
    float G[81], wsum[9];
#pragma unroll
    for (int k = 0; k < 81; ++k) G[k] = gw[k];
#pragma unroll
    for (int c = 0; c < 9; ++c) wsum[c] = gw[81 + c];

    float a1_0 = 0.f, a2_0 = 0.f;  // j0 = 2p  (n=0)
    float a1_1 = 0.f, a2_1 = 0.f;  // j1 = 2p+1 (n=1)

    const int wid = blockIdx.x * 4 + (tid >> 6);
    const int nw = gridDim.x * 4;
    for (int pr = wid; pr < npairs; pr += nw) {
        const float2* src =
            (const float2*)(pillars + (size_t)(pr * 2 + bsub) * 576 + p * 18);
        float v[18];
#pragma unroll
        for (int k = 0; k < 9; ++k) {
            const float2 t = src[k];
            v[2 * k] = t.x;
            v[2 * k + 1] = t.y;
        }
        float d0 = 0.f, d1 = 0.f, q0 = 0.f, q1 = 0.f;
#pragma unroll
        for (int c = 0; c < 9; ++c) {
            d0 = fmaf(wsum[c], v[c], d0);
            d1 = fmaf(wsum[c], v[9 + c], d1);
            float t0 = 0.f, t1 = 0.f;
#pragma unroll
            for (int c2 = 0; c2 < 9; ++c2) {
                const float g = G[c * 9 + c2];
                t0 = fmaf(g, v[c2], t0);
                t1 = fmaf(g, v[9 + c2], t1);
            }
            q0 = fmaf(v[c], t0, q0);
            q1 = fmaf(v[9 + c], t1, q1);
        }
        a1_0 += d0; a2_0 += q0;
        a1_1 += d1; a2_1 += q1;
    }

    __shared__ float red[256][5];  // padded: stride 5 kills bank aliasing
    red[tid][0] = a1_0; red[tid][1] = a2_0;
    red[tid][2] = a1_1; red[tid][3] = a2_1;
    __syncthreads();
    if (tid < 32) {  // thread tid handles p = tid (rows tid + 32k, k<8)
        float s0 = 0.f, s1 = 0.f, s2 = 0.f, s3 = 0.f;
#pragma unroll
        for (int k = 0; k < 8; ++k) {
            s0 += red[tid + 32 * k][0];
            s1 += red[tid + 32 * k][1];
            s2 += red[tid + 32 * k][2];
            s3 += red[tid + 32 * k][3];
        }
        float* acc = acc8 + (blockIdx.x & 7) * 128;
        atomicAdd(&acc[(2 * tid) * 2], s0);
        atomicAdd(&acc[(2 * tid) * 2 + 1], s1);
        atomicAdd(&acc[(2 * tid + 1) * 2], s2);
        atomicAdd(&acc[(2 * tid + 1) * 2 + 1], s3);
    }
}

__global__ __launch_bounds__(256) void pfn_main(const float* __restrict__ pillars,
                                                const float* __restrict__ W,
                                                const float* __restrict__ acc8,
                                                const float* __restrict__ gamma,
                                                const float* __restrict__ beta,
                                                float* __restrict__ out,
                                                int npairs, float invBC) {
    __shared__ float coefA[64], coefB[64];
    const int tid = threadIdx.x;
    // Inline finalize: thread j<64 computes BN coeffs for column j from the
    // L2-hot shadow accumulators (same math as the old pfn_finalize).
    if (tid < 64) {
        float s1 = 0.f, s2 = 0.f;
#pragma unroll
        for (int s = 0; s < 8; ++s) {
            s1 += acc8[s * 128 + tid * 2];
            s2 += acc8[s * 128 + tid * 2 + 1];
        }
        const float mean = s1 * invBC;
        const float var = s2 * invBC - mean * mean;
        const float a = rsqrtf(var + EPS_BN) * gamma[tid];
        coefA[tid] = a;
        coefB[tid] = beta[tid] - mean * a;
    }
    __syncthreads();

    const int lane = tid & 63;
    const int p = lane & 31;
    const int bsub = lane >> 5;
    const float a0 = coefA[2 * p], a1 = coefA[2 * p + 1];
    const float b0 = coefB[2 * p], b1 = coefB[2 * p + 1];

    const int pr = blockIdx.x * 4 + (tid >> 6);
    if (pr >= npairs) return;
    const int b = pr * 2 + bsub;

    float v[18];
    const float2* src = (const float2*)(pillars + (size_t)b * 576 + p * 18);
#pragma unroll
    for (int k = 0; k < 9; ++k) {
        const float2 t = src[k];
        v[2 * k] = t.x;
        v[2 * k + 1] = t.y;
    }

    float* Ob = out + (size_t)b * 2048 + p;
#pragma unroll 4
    for (int o = 0; o < 64; ++o) {
        float x0 = 0.f, x1 = 0.f;
#pragma unroll
        for (int c = 0; c < 9; ++c) {
            const float w = W[o * 9 + c];  // wave-uniform -> s_load, K$-hot
            x0 = fmaf(w, v[c], x0);
            x1 = fmaf(w, v[9 + c], x1);
        }
        const float r0 = fmaxf(fmaf(x0, a0, b0), 0.f);
        const float r1 = fmaxf(fmaf(x1, a1, b1), 0.f);
        Ob[o * 32] = fmaxf(r0, r1);  // lanes 0-31 -> b, 32-63 -> b+1: 2x128B segs
    }
}

extern "C" void kernel_launch(void* const* d_in, const int* in_sizes, int n_in,
                              void* d_out, int out_size, void* d_ws, size_t ws_size,
                              hipStream_t stream) {
    const float* pillars = (const float*)d_in[0];
    // d_in[1] = num_points_per_pillar: unused by the reference computation
    const float* W = (const float*)d_in[2];
    const float* gamma = (const float*)d_in[3];
    const float* beta = (const float*)d_in[4];
    float* out = (float*)d_out;
    float* ws = (float*)d_ws;

    const int B = in_sizes[0] / 576;  // 16384
    const int npairs = B / 2;
    const float invBC = 1.0f / ((float)B * 64.0f);

    pfn_prep<<<1, 64, 0, stream>>>(W, ws);
    pfn_stats<<<1024, 256, 0, stream>>>(pillars, ws, ws + 96, npairs);
    pfn_main<<<2048, 256, 0, stream>>>(pillars, W, ws + 96, gamma, beta, out,
                                       npairs, invBC);
}